// Round 4
// baseline (111.315 us; speedup 1.0000x reference)
//
#include <hip/hip_runtime.h>
#include <hip/hip_bf16.h>
#include <math.h>

#define N_Q     16384
#define DDIM    512
#define M_SLOTS 2048
#define EPSN    1e-12f
#define TEMPU   1e-5f

typedef unsigned int u32;
typedef unsigned long long u64;
typedef __attribute__((ext_vector_type(8))) short bf16x8;
typedef __attribute__((ext_vector_type(4))) float f32x4;

// ---------- helpers ----------
__device__ __forceinline__ u32 mapf(float f) {
    u32 b = __float_as_uint(f);
    return (b & 0x80000000u) ? ~b : (b | 0x80000000u);
}
__device__ __forceinline__ float unmapf(u32 u) {
    u32 b = (u & 0x80000000u) ? (u ^ 0x80000000u) : ~u;
    return __uint_as_float(b);
}
__device__ __forceinline__ float bf2f(unsigned short u) {
    return __uint_as_float(((u32)u) << 16);
}
__device__ __forceinline__ unsigned short f2bf(float f) {
    u32 b = __float_as_uint(f);
    u32 r = (b + 0x7FFFu + ((b >> 16) & 1u)) >> 16;  // RNE
    return (unsigned short)r;
}
__device__ __forceinline__ void gld_lds16(const unsigned short* g, unsigned short* l) {
    __builtin_amdgcn_global_load_lds(
        (const __attribute__((address_space(1))) u32*)(g),
        (__attribute__((address_space(3))) u32*)(l), 16, 0, 0);
}
__device__ __forceinline__ float block_reduce_sum_128(float v, float* sred, int t) {
    #pragma unroll
    for (int o = 32; o > 0; o >>= 1) v += __shfl_down(v, o, 64);
    if ((t & 63) == 0) sred[t >> 6] = v;
    __syncthreads();
    return sred[0] + sred[1];
}

// ---------- kernel 1: normalize queries (blocks 0..N_Q-1) + keys->bf16 (last 2048) ----------
__global__ __launch_bounds__(128) void k_prep(const float* __restrict__ q,
                                              const float* __restrict__ keys,
                                              unsigned short* __restrict__ qbf,
                                              unsigned short* __restrict__ keysbf) {
    __shared__ float sred[2];
    int b = blockIdx.x;
    int t = threadIdx.x;
    if (b < N_Q) {
        float4 v = ((const float4*)(q + (size_t)b * DDIM))[t];
        float ss = v.x * v.x + v.y * v.y + v.z * v.z + v.w * v.w;
        ss = block_reduce_sum_128(ss, sred, t);
        float inv = 1.0f / fmaxf(sqrtf(ss), EPSN);
        ushort4 o4;
        o4.x = f2bf(v.x * inv);
        o4.y = f2bf(v.y * inv);
        o4.z = f2bf(v.z * inv);
        o4.w = f2bf(v.w * inv);
        ((ushort4*)(qbf + (size_t)b * DDIM))[t] = o4;
    } else {
        int r = b - N_Q;
        float4 v = ((const float4*)(keys + (size_t)r * DDIM))[t];
        ushort4 o4;
        o4.x = f2bf(v.x);
        o4.y = f2bf(v.y);
        o4.z = f2bf(v.z);
        o4.w = f2bf(v.w);
        ((ushort4*)(keysbf + (size_t)r * DDIM))[t] = o4;
    }
}

// ---------- kernel 2: MFMA score GEMM + fused row-argmax / col-max ----------
// 128x128 tile, BK=32, 4 waves 2x2. LDS chunk-swizzle: chunk c of row r sits at
// slot c ^ ((r ^ (r>>2)) & 3)  -> every 8-lane phase of ds_read_b128 hits 8
// distinct 16B slots (conflict-free). Staged via per-lane-swizzled global src
// (linear global_load_lds dest, per G21).
__global__ __launch_bounds__(256) void k_score(const unsigned short* __restrict__ qbf,
                                               const unsigned short* __restrict__ keysbf,
                                               u64* __restrict__ rowpack,
                                               u32* __restrict__ colmax) {
    __shared__ unsigned short sA[128 * 32];
    __shared__ unsigned short sB[128 * 32];

    int t = threadIdx.x;
    int lane = t & 63;
    int wid = t >> 6;
    int wrow = wid >> 1;
    int wcol = wid & 1;
    int lr = lane & 15;          // frag row (A) / col (B)
    int kc = lane >> 4;          // k-chunk 0..3

    // XCD-chunked swizzle: XCD x gets logical nb in [x*16, x*16+16) for all jb
    // -> per-XCD working set = 2MB qbf slice + 2MB keysbf = L2-resident
    int bid = blockIdx.x;
    int lid = (bid & 7) * 256 + (bid >> 3);
    int jb = lid & 15;
    int nb = lid >> 4;
    int n0 = nb * 128;
    int j0 = jb * 128;

    // staging: thread t covers tile row srow=t>>2, LDS slot t&3; the global
    // chunk fetched there is the swizzle-inverse
    int srow = t >> 2;
    int gchunk = (t & 3) ^ ((srow ^ (srow >> 2)) & 3);
    int scol = gchunk * 8;       // bf16 elements within the 32-wide K-slab

    // read-side swizzled chunk (row bits reduce to lr bits for 16-aligned frags)
    int kcs = kc ^ ((lr ^ (lr >> 2)) & 3);

    f32x4 acc[4][4] = {};

    for (int k0 = 0; k0 < DDIM; k0 += 32) {
        __syncthreads();
        gld_lds16(qbf + (size_t)(n0 + srow) * DDIM + k0 + scol,         sA + t * 8);
        gld_lds16(qbf + (size_t)(n0 + 64 + srow) * DDIM + k0 + scol,    sA + 2048 + t * 8);
        gld_lds16(keysbf + (size_t)(j0 + srow) * DDIM + k0 + scol,      sB + t * 8);
        gld_lds16(keysbf + (size_t)(j0 + 64 + srow) * DDIM + k0 + scol, sB + 2048 + t * 8);
        __syncthreads();

        bf16x8 a[4], b[4];
        #pragma unroll
        for (int i = 0; i < 4; ++i)
            a[i] = *(const bf16x8*)(sA + (wrow * 64 + i * 16 + lr) * 32 + kcs * 8);
        #pragma unroll
        for (int j = 0; j < 4; ++j)
            b[j] = *(const bf16x8*)(sB + (wcol * 64 + j * 16 + lr) * 32 + kcs * 8);
        #pragma unroll
        for (int i = 0; i < 4; ++i)
            #pragma unroll
            for (int j = 0; j < 4; ++j)
                acc[i][j] = __builtin_amdgcn_mfma_f32_16x16x32_bf16(a[i], b[j], acc[i][j], 0, 0, 0);
    }

    // ---- fused epilogue ----
    // C/D layout: col = lane&15 (=lr), row = (lane>>4)*4 + reg (=kc*4+r)
    #pragma unroll
    for (int i = 0; i < 4; ++i) {
        #pragma unroll
        for (int r = 0; r < 4; ++r) {
            float v = acc[i][0][r];
            int c = j0 + wcol * 64 + lr;
            #pragma unroll
            for (int j = 1; j < 4; ++j) {
                float vj = acc[i][j][r];
                int cj = j0 + wcol * 64 + j * 16 + lr;
                if (vj > v) { v = vj; c = cj; }
            }
            #pragma unroll
            for (int off = 1; off < 16; off <<= 1) {
                float ov = __shfl_xor(v, off, 64);
                int oc = __shfl_xor(c, off, 64);
                if (ov > v || (ov == v && oc < c)) { v = ov; c = oc; }
            }
            if (lr == 0) {
                int grow = n0 + wrow * 64 + i * 16 + kc * 4 + r;
                u64 pk = ((u64)mapf(v) << 32) | (u64)(~(u32)c);  // ~col: ties -> lower col
                atomicMax(rowpack + grow, pk);
            }
        }
    }
    #pragma unroll
    for (int j = 0; j < 4; ++j) {
        float m = acc[0][j][0];
        #pragma unroll
        for (int i = 0; i < 4; ++i)
            #pragma unroll
            for (int r = 0; r < 4; ++r) m = fmaxf(m, acc[i][j][r]);
        m = fmaxf(m, __shfl_xor(m, 16, 64));
        m = fmaxf(m, __shfl_xor(m, 32, 64));
        if (kc == 0) atomicMax(colmax + j0 + wcol * 64 + j * 16 + lr, mapf(m));
    }
}

// ---------- kernel 3a: histogram of argmax slots ----------
__global__ __launch_bounds__(256) void k_hist(const u64* __restrict__ rowpack,
                                              u32* __restrict__ cnt) {
    int n = blockIdx.x * 256 + threadIdx.x;
    u64 p = rowpack[n];
    int g = (int)(~(u32)(p & 0xFFFFFFFFull));
    atomicAdd(cnt + g, 1u);
}

// ---------- kernel 3b: exclusive scan over 2048 counts (1 block, shfl) ----------
__global__ __launch_bounds__(256) void k_scan(const u32* __restrict__ cnt,
                                              u32* __restrict__ start,
                                              u32* __restrict__ cursor) {
    __shared__ u32 wsum[4];
    int t = threadIdx.x;
    int lane = t & 63, w = t >> 6;
    u32 local[8], s = 0;
    #pragma unroll
    for (int i = 0; i < 8; ++i) { local[i] = cnt[t * 8 + i]; s += local[i]; }
    // inclusive wave scan of s
    u32 x = s;
    #pragma unroll
    for (int off = 1; off < 64; off <<= 1) {
        u32 y = __shfl_up(x, off, 64);
        if (lane >= off) x += y;
    }
    if (lane == 63) wsum[w] = x;
    __syncthreads();
    u32 base = 0;
    #pragma unroll
    for (int i = 0; i < 4; ++i) if (i < w) base += wsum[i];
    u32 run = base + x - s;   // exclusive prefix for this thread's 8 slots
    #pragma unroll
    for (int i = 0; i < 8; ++i) {
        start[t * 8 + i] = run;
        cursor[t * 8 + i] = run;
        run += local[i];
    }
}

// ---------- kernel 3c: fill perm + weights ----------
__global__ __launch_bounds__(256) void k_fill(const u64* __restrict__ rowpack,
                                              const u32* __restrict__ colmax,
                                              u32* __restrict__ cursor,
                                              u32* __restrict__ perm,
                                              float* __restrict__ wval) {
    int n = blockIdx.x * 256 + threadIdx.x;
    u64 p = rowpack[n];
    float val = unmapf((u32)(p >> 32));
    int g = (int)(~(u32)(p & 0xFFFFFFFFull));
    float cm = unmapf(colmax[g]);
    float w = expf(val - cm);   // <= 1
    u32 pos = atomicAdd(cursor + g, 1u);
    perm[pos] = (u32)n;
    wval[pos] = w;
}

// ---------- kernel 4: gather + final normalize (fused) ----------
__global__ __launch_bounds__(128) void k_gather_final(const unsigned short* __restrict__ qbf,
                                                      const u32* __restrict__ start,
                                                      const u32* __restrict__ cnt,
                                                      const u32* __restrict__ perm,
                                                      const float* __restrict__ wval,
                                                      const float* __restrict__ keys,
                                                      float* __restrict__ out) {
    __shared__ float sred[2];
    int j = blockIdx.x;
    int t = threadIdx.x;
    u32 s = start[j];
    u32 e = s + cnt[j];
    float ax = 0.f, ay = 0.f, az = 0.f, aw = 0.f;
    for (u32 i = s; i < e; ++i) {
        u32 n = perm[i];
        float w = wval[i];
        ushort4 u4 = ((const ushort4*)(qbf + (size_t)n * DDIM))[t];
        ax = fmaf(w, bf2f(u4.x), ax);
        ay = fmaf(w, bf2f(u4.y), ay);
        az = fmaf(w, bf2f(u4.z), az);
        aw = fmaf(w, bf2f(u4.w), aw);
    }
    float4 k4 = ((const float4*)(keys + (size_t)j * DDIM))[t];
    float4 v;
    v.x = fmaf(TEMPU, ax, k4.x);
    v.y = fmaf(TEMPU, ay, k4.y);
    v.z = fmaf(TEMPU, az, k4.z);
    v.w = fmaf(TEMPU, aw, k4.w);
    float ss = v.x * v.x + v.y * v.y + v.z * v.z + v.w * v.w;
    ss = block_reduce_sum_128(ss, sred, t);
    float inv = 1.0f / fmaxf(sqrtf(ss), EPSN);
    v.x *= inv; v.y *= inv; v.z *= inv; v.w *= inv;
    ((float4*)(out + (size_t)j * DDIM))[t] = v;
}

// ---------- launch ----------
extern "C" void kernel_launch(void* const* d_in, const int* in_sizes, int n_in,
                              void* d_out, int out_size, void* d_ws, size_t ws_size,
                              hipStream_t stream) {
    const float* query = (const float*)d_in[0];   // [16384, 512] f32
    const float* keys  = (const float*)d_in[1];   // [2048, 512] f32
    float* out = (float*)d_out;                   // [2048, 512] f32

    char* ws = (char*)d_ws;
    const size_t OFF_QBF   = 0;                        // 16,777,216 B
    const size_t OFF_ROW   = 16777216;                 //    131,072 B  rowpack u64[16384]
    const size_t OFF_CMAX  = OFF_ROW + 131072;         //      8,192 B
    const size_t OFF_CNT   = OFF_CMAX + 8192;          //      8,192 B
    const size_t OFF_START = OFF_CNT + 8192;           //      8,192 B
    const size_t OFF_CUR   = OFF_START + 8192;         //      8,192 B
    const size_t OFF_PERM  = OFF_CUR + 8192;           //     65,536 B
    const size_t OFF_W     = OFF_PERM + 65536;         //     65,536 B
    const size_t OFF_KBF   = OFF_W + 65536;            //  2,097,152 B

    unsigned short* qbf    = (unsigned short*)(ws + OFF_QBF);
    u64*            rowpack= (u64*)(ws + OFF_ROW);
    u32*            cmax   = (u32*)(ws + OFF_CMAX);
    u32*            cnt    = (u32*)(ws + OFF_CNT);
    u32*            start  = (u32*)(ws + OFF_START);
    u32*            cursor = (u32*)(ws + OFF_CUR);
    u32*            perm   = (u32*)(ws + OFF_PERM);
    float*          wval   = (float*)(ws + OFF_W);
    unsigned short* keysbf = (unsigned short*)(ws + OFF_KBF);

    // zero rowpack + colmax + cnt (0 acts as -inf under mapf packing)
    hipMemsetAsync(ws + OFF_ROW, 0, 131072 + 8192 + 8192, stream);

    k_prep<<<N_Q + M_SLOTS, 128, 0, stream>>>(query, keys, qbf, keysbf);

    k_score<<<2048, 256, 0, stream>>>(qbf, keysbf, rowpack, cmax);

    k_hist<<<N_Q / 256, 256, 0, stream>>>(rowpack, cnt);
    k_scan<<<1, 256, 0, stream>>>(cnt, start, cursor);
    k_fill<<<N_Q / 256, 256, 0, stream>>>(rowpack, cmax, cursor, perm, wval);
    k_gather_final<<<M_SLOTS, 128, 0, stream>>>(qbf, start, cnt, perm, wval, keys, out);
}

// Round 5
// 105.794 us; speedup vs baseline: 1.0522x; 1.0522x over previous
//
#include <hip/hip_runtime.h>
#include <hip/hip_bf16.h>
#include <math.h>

#define N_Q     16384
#define DDIM    512
#define M_SLOTS 2048
#define EPSN    1e-12f
#define TEMPU   1e-5f

typedef unsigned int u32;
typedef unsigned long long u64;
typedef __attribute__((ext_vector_type(8))) short bf16x8;
typedef __attribute__((ext_vector_type(4))) float f32x4;

// ---------- helpers ----------
__device__ __forceinline__ u32 mapf(float f) {
    u32 b = __float_as_uint(f);
    return (b & 0x80000000u) ? ~b : (b | 0x80000000u);
}
__device__ __forceinline__ float unmapf(u32 u) {
    u32 b = (u & 0x80000000u) ? (u ^ 0x80000000u) : ~u;
    return __uint_as_float(b);
}
__device__ __forceinline__ float bf2f(unsigned short u) {
    return __uint_as_float(((u32)u) << 16);
}
__device__ __forceinline__ unsigned short f2bf(float f) {
    u32 b = __float_as_uint(f);
    u32 r = (b + 0x7FFFu + ((b >> 16) & 1u)) >> 16;  // RNE
    return (unsigned short)r;
}
__device__ __forceinline__ void gld_lds16(const unsigned short* g, unsigned short* l) {
    __builtin_amdgcn_global_load_lds(
        (const __attribute__((address_space(1))) u32*)(g),
        (__attribute__((address_space(3))) u32*)(l), 16, 0, 0);
}
__device__ __forceinline__ float block_reduce_sum_128(float v, float* sred, int t) {
    #pragma unroll
    for (int o = 32; o > 0; o >>= 1) v += __shfl_down(v, o, 64);
    if ((t & 63) == 0) sred[t >> 6] = v;
    __syncthreads();
    return sred[0] + sred[1];
}

// ---------- kernel 1: normalize queries (blocks 0..N_Q-1) + keys->bf16 (last 2048) ----------
__global__ __launch_bounds__(128) void k_prep(const float* __restrict__ q,
                                              const float* __restrict__ keys,
                                              unsigned short* __restrict__ qbf,
                                              unsigned short* __restrict__ keysbf) {
    __shared__ float sred[2];
    int b = blockIdx.x;
    int t = threadIdx.x;
    if (b < N_Q) {
        float4 v = ((const float4*)(q + (size_t)b * DDIM))[t];
        float ss = v.x * v.x + v.y * v.y + v.z * v.z + v.w * v.w;
        ss = block_reduce_sum_128(ss, sred, t);
        float inv = 1.0f / fmaxf(sqrtf(ss), EPSN);
        ushort4 o4;
        o4.x = f2bf(v.x * inv);
        o4.y = f2bf(v.y * inv);
        o4.z = f2bf(v.z * inv);
        o4.w = f2bf(v.w * inv);
        ((ushort4*)(qbf + (size_t)b * DDIM))[t] = o4;
    } else {
        int r = b - N_Q;
        float4 v = ((const float4*)(keys + (size_t)r * DDIM))[t];
        ushort4 o4;
        o4.x = f2bf(v.x);
        o4.y = f2bf(v.y);
        o4.z = f2bf(v.z);
        o4.w = f2bf(v.w);
        ((ushort4*)(keysbf + (size_t)r * DDIM))[t] = o4;
    }
}

// ---------- kernel 2: MFMA score GEMM, 2-phase double-buffered ----------
// 128x128 tile, BK=32, 16 K-steps, 4 waves 2x2. LDS linear (round-4 showed the
// 4.19M bank conflicts are the global_load_lds write port, not ds_read).
// T3 minimum-2-phase: issue next tile's global_load_lds BEFORE computing the
// current tile; single __syncthreads (full drain) per K-step.
__global__ __launch_bounds__(256) void k_score(const unsigned short* __restrict__ qbf,
                                               const unsigned short* __restrict__ keysbf,
                                               u64* __restrict__ rowpack,
                                               u32* __restrict__ colmax) {
    __shared__ unsigned short sA[2][128 * 32];
    __shared__ unsigned short sB[2][128 * 32];

    int t = threadIdx.x;
    int lane = t & 63;
    int wid = t >> 6;
    int wrow = wid >> 1;
    int wcol = wid & 1;
    int lr = lane & 15;          // frag row (A) / col (B)
    int kc = lane >> 4;          // k-chunk 0..3

    int n0 = blockIdx.y * 128;   // query block
    int j0 = blockIdx.x * 128;   // slot block

    int srow = t >> 2;
    int scol = (t & 3) * 8;      // bf16 elements within the 32-wide K-slab

    const unsigned short* gA0 = qbf    + (size_t)(n0 + srow) * DDIM + scol;
    const unsigned short* gA1 = qbf    + (size_t)(n0 + 64 + srow) * DDIM + scol;
    const unsigned short* gB0 = keysbf + (size_t)(j0 + srow) * DDIM + scol;
    const unsigned short* gB1 = keysbf + (size_t)(j0 + 64 + srow) * DDIM + scol;

    f32x4 acc[4][4] = {};

#define STAGE(buf, k0)  do {                                   \
        gld_lds16(gA0 + (k0), &sA[buf][t * 8]);                \
        gld_lds16(gA1 + (k0), &sA[buf][2048 + t * 8]);         \
        gld_lds16(gB0 + (k0), &sB[buf][t * 8]);                \
        gld_lds16(gB1 + (k0), &sB[buf][2048 + t * 8]);         \
    } while (0)

    STAGE(0, 0);
    __syncthreads();             // drain: buf0 ready

    #pragma unroll
    for (int kt = 0; kt < 16; ++kt) {
        const int cur = kt & 1;
        if (kt < 15) STAGE(cur ^ 1, (kt + 1) * 32);   // prefetch next tile

        bf16x8 a[4], b[4];
        #pragma unroll
        for (int i = 0; i < 4; ++i)
            a[i] = *(const bf16x8*)&sA[cur][(wrow * 64 + i * 16 + lr) * 32 + kc * 8];
        #pragma unroll
        for (int j = 0; j < 4; ++j)
            b[j] = *(const bf16x8*)&sB[cur][(wcol * 64 + j * 16 + lr) * 32 + kc * 8];
        #pragma unroll
        for (int i = 0; i < 4; ++i)
            #pragma unroll
            for (int j = 0; j < 4; ++j)
                acc[i][j] = __builtin_amdgcn_mfma_f32_16x16x32_bf16(a[i], b[j], acc[i][j], 0, 0, 0);

        if (kt < 15) __syncthreads();   // drains vmcnt(0): next buffer landed,
                                        // and all waves done reading buf[cur]
    }
#undef STAGE

    // ---- fused epilogue ----
    // C/D layout: col = lane&15 (=lr), row = (lane>>4)*4 + reg (=kc*4+r)
    #pragma unroll
    for (int i = 0; i < 4; ++i) {
        #pragma unroll
        for (int r = 0; r < 4; ++r) {
            float v = acc[i][0][r];
            int c = j0 + wcol * 64 + lr;
            #pragma unroll
            for (int j = 1; j < 4; ++j) {
                float vj = acc[i][j][r];
                int cj = j0 + wcol * 64 + j * 16 + lr;
                if (vj > v) { v = vj; c = cj; }
            }
            #pragma unroll
            for (int off = 1; off < 16; off <<= 1) {
                float ov = __shfl_xor(v, off, 64);
                int oc = __shfl_xor(c, off, 64);
                if (ov > v || (ov == v && oc < c)) { v = ov; c = oc; }
            }
            if (lr == 0) {
                int grow = n0 + wrow * 64 + i * 16 + kc * 4 + r;
                u64 pk = ((u64)mapf(v) << 32) | (u64)(~(u32)c);  // ~col: ties -> lower col
                atomicMax(rowpack + grow, pk);
            }
        }
    }
    #pragma unroll
    for (int j = 0; j < 4; ++j) {
        float m = acc[0][j][0];
        #pragma unroll
        for (int i = 0; i < 4; ++i)
            #pragma unroll
            for (int r = 0; r < 4; ++r) m = fmaxf(m, acc[i][j][r]);
        m = fmaxf(m, __shfl_xor(m, 16, 64));
        m = fmaxf(m, __shfl_xor(m, 32, 64));
        if (kc == 0) atomicMax(colmax + j0 + wcol * 64 + j * 16 + lr, mapf(m));
    }
}

// ---------- kernel 3a: histogram of argmax slots ----------
__global__ __launch_bounds__(256) void k_hist(const u64* __restrict__ rowpack,
                                              u32* __restrict__ cnt) {
    int n = blockIdx.x * 256 + threadIdx.x;
    u64 p = rowpack[n];
    int g = (int)(~(u32)(p & 0xFFFFFFFFull));
    atomicAdd(cnt + g, 1u);
}

// ---------- kernel 3b: exclusive scan over 2048 counts (1 block, shfl) ----------
__global__ __launch_bounds__(256) void k_scan(const u32* __restrict__ cnt,
                                              u32* __restrict__ start,
                                              u32* __restrict__ cursor) {
    __shared__ u32 wsum[4];
    int t = threadIdx.x;
    int lane = t & 63, w = t >> 6;
    u32 local[8], s = 0;
    #pragma unroll
    for (int i = 0; i < 8; ++i) { local[i] = cnt[t * 8 + i]; s += local[i]; }
    u32 x = s;
    #pragma unroll
    for (int off = 1; off < 64; off <<= 1) {
        u32 y = __shfl_up(x, off, 64);
        if (lane >= off) x += y;
    }
    if (lane == 63) wsum[w] = x;
    __syncthreads();
    u32 base = 0;
    #pragma unroll
    for (int i = 0; i < 4; ++i) if (i < w) base += wsum[i];
    u32 run = base + x - s;
    #pragma unroll
    for (int i = 0; i < 8; ++i) {
        start[t * 8 + i] = run;
        cursor[t * 8 + i] = run;
        run += local[i];
    }
}

// ---------- kernel 3c: fill perm + weights ----------
__global__ __launch_bounds__(256) void k_fill(const u64* __restrict__ rowpack,
                                              const u32* __restrict__ colmax,
                                              u32* __restrict__ cursor,
                                              u32* __restrict__ perm,
                                              float* __restrict__ wval) {
    int n = blockIdx.x * 256 + threadIdx.x;
    u64 p = rowpack[n];
    float val = unmapf((u32)(p >> 32));
    int g = (int)(~(u32)(p & 0xFFFFFFFFull));
    float cm = unmapf(colmax[g]);
    float w = expf(val - cm);   // <= 1
    u32 pos = atomicAdd(cursor + g, 1u);
    perm[pos] = (u32)n;
    wval[pos] = w;
}

// ---------- kernel 4: gather + final normalize (fused) ----------
__global__ __launch_bounds__(128) void k_gather_final(const unsigned short* __restrict__ qbf,
                                                      const u32* __restrict__ start,
                                                      const u32* __restrict__ cnt,
                                                      const u32* __restrict__ perm,
                                                      const float* __restrict__ wval,
                                                      const float* __restrict__ keys,
                                                      float* __restrict__ out) {
    __shared__ float sred[2];
    int j = blockIdx.x;
    int t = threadIdx.x;
    u32 s = start[j];
    u32 e = s + cnt[j];
    float ax = 0.f, ay = 0.f, az = 0.f, aw = 0.f;
    for (u32 i = s; i < e; ++i) {
        u32 n = perm[i];
        float w = wval[i];
        ushort4 u4 = ((const ushort4*)(qbf + (size_t)n * DDIM))[t];
        ax = fmaf(w, bf2f(u4.x), ax);
        ay = fmaf(w, bf2f(u4.y), ay);
        az = fmaf(w, bf2f(u4.z), az);
        aw = fmaf(w, bf2f(u4.w), aw);
    }
    float4 k4 = ((const float4*)(keys + (size_t)j * DDIM))[t];
    float4 v;
    v.x = fmaf(TEMPU, ax, k4.x);
    v.y = fmaf(TEMPU, ay, k4.y);
    v.z = fmaf(TEMPU, az, k4.z);
    v.w = fmaf(TEMPU, aw, k4.w);
    float ss = v.x * v.x + v.y * v.y + v.z * v.z + v.w * v.w;
    ss = block_reduce_sum_128(ss, sred, t);
    float inv = 1.0f / fmaxf(sqrtf(ss), EPSN);
    v.x *= inv; v.y *= inv; v.z *= inv; v.w *= inv;
    ((float4*)(out + (size_t)j * DDIM))[t] = v;
}

// ---------- launch ----------
extern "C" void kernel_launch(void* const* d_in, const int* in_sizes, int n_in,
                              void* d_out, int out_size, void* d_ws, size_t ws_size,
                              hipStream_t stream) {
    const float* query = (const float*)d_in[0];   // [16384, 512] f32
    const float* keys  = (const float*)d_in[1];   // [2048, 512] f32
    float* out = (float*)d_out;                   // [2048, 512] f32

    char* ws = (char*)d_ws;
    const size_t OFF_QBF   = 0;                        // 16,777,216 B
    const size_t OFF_ROW   = 16777216;                 //    131,072 B  rowpack u64[16384]
    const size_t OFF_CMAX  = OFF_ROW + 131072;         //      8,192 B
    const size_t OFF_CNT   = OFF_CMAX + 8192;          //      8,192 B
    const size_t OFF_START = OFF_CNT + 8192;           //      8,192 B
    const size_t OFF_CUR   = OFF_START + 8192;         //      8,192 B
    const size_t OFF_PERM  = OFF_CUR + 8192;           //     65,536 B
    const size_t OFF_W     = OFF_PERM + 65536;         //     65,536 B
    const size_t OFF_KBF   = OFF_W + 65536;            //  2,097,152 B

    unsigned short* qbf    = (unsigned short*)(ws + OFF_QBF);
    u64*            rowpack= (u64*)(ws + OFF_ROW);
    u32*            cmax   = (u32*)(ws + OFF_CMAX);
    u32*            cnt    = (u32*)(ws + OFF_CNT);
    u32*            start  = (u32*)(ws + OFF_START);
    u32*            cursor = (u32*)(ws + OFF_CUR);
    u32*            perm   = (u32*)(ws + OFF_PERM);
    float*          wval   = (float*)(ws + OFF_W);
    unsigned short* keysbf = (unsigned short*)(ws + OFF_KBF);

    // zero rowpack + colmax + cnt (0 acts as -inf under mapf packing)
    hipMemsetAsync(ws + OFF_ROW, 0, 131072 + 8192 + 8192, stream);

    k_prep<<<N_Q + M_SLOTS, 128, 0, stream>>>(query, keys, qbf, keysbf);

    dim3 g2(M_SLOTS / 128, N_Q / 128);  // 16 x 128
    k_score<<<g2, 256, 0, stream>>>(qbf, keysbf, rowpack, cmax);

    k_hist<<<N_Q / 256, 256, 0, stream>>>(rowpack, cnt);
    k_scan<<<1, 256, 0, stream>>>(cnt, start, cursor);
    k_fill<<<N_Q / 256, 256, 0, stream>>>(rowpack, cmax, cursor, perm, wval);
    k_gather_final<<<M_SLOTS, 128, 0, stream>>>(qbf, start, cnt, perm, wval, keys, out);
}

// Round 6
// 86.972 us; speedup vs baseline: 1.2799x; 1.2164x over previous
//
#include <hip/hip_runtime.h>
#include <math.h>

#define N_Q     16384
#define DDIM    512
#define M_SLOTS 2048
#define EPSN    1e-12f
#define TEMPU   1e-5f
#define KSCALE  25.4f                    // int8 scale for keys (clips at ~5 sigma)
#define QSCALE  127.0f
#define INV_S   (1.0f / (127.0f * 25.4f))

typedef unsigned int u32;
typedef unsigned long long u64;
typedef __attribute__((ext_vector_type(4))) int i32x4;

// ---------- helpers ----------
__device__ __forceinline__ void gld_lds16(const void* g, void* l) {
    __builtin_amdgcn_global_load_lds(
        (const __attribute__((address_space(1))) u32*)(g),
        (__attribute__((address_space(3))) u32*)(l), 16, 0, 0);
}
__device__ __forceinline__ float block_reduce_sum_128(float v, float* sred, int t) {
    #pragma unroll
    for (int o = 32; o > 0; o >>= 1) v += __shfl_down(v, o, 64);
    if ((t & 63) == 0) sred[t >> 6] = v;
    __syncthreads();
    return sred[0] + sred[1];
}
__device__ __forceinline__ char q8(float x, float s) {
    int v = __float2int_rn(x * s);
    v = v < -127 ? -127 : (v > 127 ? 127 : v);
    return (char)v;
}

// ---------- kernel 1: normalize+quantize queries (blocks 0..N_Q-1), keys->i8 (last 2048) ----------
__global__ __launch_bounds__(128) void k_prep(const float* __restrict__ q,
                                              const float* __restrict__ keys,
                                              char* __restrict__ qi8,
                                              char* __restrict__ ki8) {
    __shared__ float sred[2];
    int b = blockIdx.x;
    int t = threadIdx.x;
    if (b < N_Q) {
        float4 v = ((const float4*)(q + (size_t)b * DDIM))[t];
        float ss = v.x * v.x + v.y * v.y + v.z * v.z + v.w * v.w;
        ss = block_reduce_sum_128(ss, sred, t);
        float s = QSCALE / fmaxf(sqrtf(ss), EPSN);
        char4 o;
        o.x = q8(v.x, s);
        o.y = q8(v.y, s);
        o.z = q8(v.z, s);
        o.w = q8(v.w, s);
        ((char4*)(qi8 + (size_t)b * DDIM))[t] = o;
    } else {
        int r = b - N_Q;
        float4 v = ((const float4*)(keys + (size_t)r * DDIM))[t];
        char4 o;
        o.x = q8(v.x, KSCALE);
        o.y = q8(v.y, KSCALE);
        o.z = q8(v.z, KSCALE);
        o.w = q8(v.w, KSCALE);
        ((char4*)(ki8 + (size_t)r * DDIM))[t] = o;
    }
}

// ---------- kernel 2: i8 MFMA score GEMM + fused row-argmax / col-max ----------
// 128x128 tile, BK=64 (i8), 8 K-steps, 4 waves 2x2, mfma_i32_16x16x64_i8.
// Byte geometry identical to the bf16 BK=32 version (64B rows, 32KB LDS dbuf).
__global__ __launch_bounds__(256) void k_score(const char* __restrict__ qi8,
                                               const char* __restrict__ ki8,
                                               u64* __restrict__ rowpack,
                                               int* __restrict__ colmax) {
    __shared__ char sA[2][128 * 64];
    __shared__ char sB[2][128 * 64];

    int t = threadIdx.x;
    int lane = t & 63;
    int wid = t >> 6;
    int wrow = wid >> 1;
    int wcol = wid & 1;
    int lr = lane & 15;          // frag row (A) / col (B)
    int kc = lane >> 4;          // k-chunk 0..3 (16 i8 each)

    int n0 = blockIdx.y * 128;   // query block
    int j0 = blockIdx.x * 128;   // slot block

    int srow = t >> 2;
    int scolB = (t & 3) * 16;    // byte offset within 64B row

    const char* gA0 = qi8 + (size_t)(n0 + srow) * DDIM + scolB;
    const char* gA1 = qi8 + (size_t)(n0 + 64 + srow) * DDIM + scolB;
    const char* gB0 = ki8 + (size_t)(j0 + srow) * DDIM + scolB;
    const char* gB1 = ki8 + (size_t)(j0 + 64 + srow) * DDIM + scolB;

    i32x4 acc[4][4] = {};

#define STAGE(buf, k0)  do {                                   \
        gld_lds16(gA0 + (k0), &sA[buf][t * 16]);               \
        gld_lds16(gA1 + (k0), &sA[buf][4096 + t * 16]);        \
        gld_lds16(gB0 + (k0), &sB[buf][t * 16]);               \
        gld_lds16(gB1 + (k0), &sB[buf][4096 + t * 16]);        \
    } while (0)

    STAGE(0, 0);
    __syncthreads();

    #pragma unroll
    for (int kt = 0; kt < 8; ++kt) {
        const int cur = kt & 1;
        if (kt < 7) STAGE(cur ^ 1, (kt + 1) * 64);

        i32x4 a[4], b[4];
        #pragma unroll
        for (int i = 0; i < 4; ++i)
            a[i] = *(const i32x4*)&sA[cur][(wrow * 64 + i * 16 + lr) * 64 + kc * 16];
        #pragma unroll
        for (int j = 0; j < 4; ++j)
            b[j] = *(const i32x4*)&sB[cur][(wcol * 64 + j * 16 + lr) * 64 + kc * 16];
        #pragma unroll
        for (int i = 0; i < 4; ++i)
            #pragma unroll
            for (int j = 0; j < 4; ++j)
                acc[i][j] = __builtin_amdgcn_mfma_i32_16x16x64_i8(a[i], b[j], acc[i][j], 0, 0, 0);

        if (kt < 7) __syncthreads();
    }
#undef STAGE

    // ---- fused epilogue (int scores) ----
    // C/D layout: col = lane&15 (=lr), row = (lane>>4)*4 + reg (=kc*4+r)
    #pragma unroll
    for (int i = 0; i < 4; ++i) {
        #pragma unroll
        for (int r = 0; r < 4; ++r) {
            int v = acc[i][0][r];
            int c = j0 + wcol * 64 + lr;
            #pragma unroll
            for (int j = 1; j < 4; ++j) {
                int vj = acc[i][j][r];
                int cj = j0 + wcol * 64 + j * 16 + lr;
                if (vj > v) { v = vj; c = cj; }    // ascending cols: keeps lowest on tie
            }
            #pragma unroll
            for (int off = 1; off < 16; off <<= 1) {
                int ov = __shfl_xor(v, off, 64);
                int oc = __shfl_xor(c, off, 64);
                if (ov > v || (ov == v && oc < c)) { v = ov; c = oc; }
            }
            if (lr == 0) {
                int grow = n0 + wrow * 64 + i * 16 + kc * 4 + r;
                u64 pk = ((u64)(u32)(v ^ 0x80000000) << 32) | (u64)(~(u32)c);
                atomicMax(rowpack + grow, pk);
            }
        }
    }
    #pragma unroll
    for (int j = 0; j < 4; ++j) {
        int m = acc[0][j][0];
        #pragma unroll
        for (int i = 0; i < 4; ++i)
            #pragma unroll
            for (int r = 0; r < 4; ++r) m = max(m, acc[i][j][r]);
        m = max(m, __shfl_xor(m, 16, 64));
        m = max(m, __shfl_xor(m, 32, 64));
        if (kc == 0) atomicMax(colmax + j0 + wcol * 64 + j * 16 + lr, m);
    }
}

// ---------- kernel 3a: histogram of argmax slots ----------
__global__ __launch_bounds__(256) void k_hist(const u64* __restrict__ rowpack,
                                              u32* __restrict__ cnt) {
    int n = blockIdx.x * 256 + threadIdx.x;
    u64 p = rowpack[n];
    int g = (int)(~(u32)(p & 0xFFFFFFFFull));
    atomicAdd(cnt + g, 1u);
}

// ---------- kernel 3b: exclusive scan over 2048 counts (1 block, shfl) ----------
__global__ __launch_bounds__(256) void k_scan(const u32* __restrict__ cnt,
                                              u32* __restrict__ start,
                                              u32* __restrict__ cursor) {
    __shared__ u32 wsum[4];
    int t = threadIdx.x;
    int lane = t & 63, w = t >> 6;
    u32 local[8], s = 0;
    #pragma unroll
    for (int i = 0; i < 8; ++i) { local[i] = cnt[t * 8 + i]; s += local[i]; }
    u32 x = s;
    #pragma unroll
    for (int off = 1; off < 64; off <<= 1) {
        u32 y = __shfl_up(x, off, 64);
        if (lane >= off) x += y;
    }
    if (lane == 63) wsum[w] = x;
    __syncthreads();
    u32 base = 0;
    #pragma unroll
    for (int i = 0; i < 4; ++i) if (i < w) base += wsum[i];
    u32 run = base + x - s;
    #pragma unroll
    for (int i = 0; i < 8; ++i) {
        start[t * 8 + i] = run;
        cursor[t * 8 + i] = run;
        run += local[i];
    }
}

// ---------- kernel 3c: fill perm + weights ----------
__global__ __launch_bounds__(256) void k_fill(const u64* __restrict__ rowpack,
                                              const int* __restrict__ colmax,
                                              u32* __restrict__ cursor,
                                              u32* __restrict__ perm,
                                              float* __restrict__ wval) {
    int n = blockIdx.x * 256 + threadIdx.x;
    u64 p = rowpack[n];
    int vi = (int)(((u32)(p >> 32)) ^ 0x80000000u);
    int g = (int)(~(u32)(p & 0xFFFFFFFFull));
    int cm = colmax[g];
    float w = expf((float)(vi - cm) * INV_S);   // <= 1
    u32 pos = atomicAdd(cursor + g, 1u);
    perm[pos] = (u32)n;
    wval[pos] = w;
}

// ---------- kernel 4: gather + final normalize (fused) ----------
__global__ __launch_bounds__(128) void k_gather_final(const char* __restrict__ qi8,
                                                      const u32* __restrict__ start,
                                                      const u32* __restrict__ cnt,
                                                      const u32* __restrict__ perm,
                                                      const float* __restrict__ wval,
                                                      const float* __restrict__ keys,
                                                      float* __restrict__ out) {
    __shared__ float sred[2];
    int j = blockIdx.x;
    int t = threadIdx.x;
    u32 s = start[j];
    u32 e = s + cnt[j];
    float ax = 0.f, ay = 0.f, az = 0.f, aw = 0.f;
    for (u32 i = s; i < e; ++i) {
        u32 n = perm[i];
        float wq = wval[i] * (1.0f / 127.0f);   // dequantized weight
        char4 q4 = ((const char4*)(qi8 + (size_t)n * DDIM))[t];
        ax = fmaf(wq, (float)q4.x, ax);
        ay = fmaf(wq, (float)q4.y, ay);
        az = fmaf(wq, (float)q4.z, az);
        aw = fmaf(wq, (float)q4.w, aw);
    }
    float4 k4 = ((const float4*)(keys + (size_t)j * DDIM))[t];
    float4 v;
    v.x = fmaf(TEMPU, ax, k4.x);
    v.y = fmaf(TEMPU, ay, k4.y);
    v.z = fmaf(TEMPU, az, k4.z);
    v.w = fmaf(TEMPU, aw, k4.w);
    float ss = v.x * v.x + v.y * v.y + v.z * v.z + v.w * v.w;
    ss = block_reduce_sum_128(ss, sred, t);
    float inv = 1.0f / fmaxf(sqrtf(ss), EPSN);
    v.x *= inv; v.y *= inv; v.z *= inv; v.w *= inv;
    ((float4*)(out + (size_t)j * DDIM))[t] = v;
}

// ---------- launch ----------
extern "C" void kernel_launch(void* const* d_in, const int* in_sizes, int n_in,
                              void* d_out, int out_size, void* d_ws, size_t ws_size,
                              hipStream_t stream) {
    const float* query = (const float*)d_in[0];   // [16384, 512] f32
    const float* keys  = (const float*)d_in[1];   // [2048, 512] f32
    float* out = (float*)d_out;                   // [2048, 512] f32

    char* ws = (char*)d_ws;
    const size_t OFF_QI8   = 0;                        //  8,388,608 B  qi8
    const size_t OFF_ROW   = 8388608;                  //    131,072 B  rowpack u64[16384]
    const size_t OFF_CNT   = OFF_ROW + 131072;         //      8,192 B  (zeroed with ROW)
    const size_t OFF_CMAX  = OFF_CNT + 8192;           //      8,192 B  (memset 0x80)
    const size_t OFF_START = OFF_CMAX + 8192;          //      8,192 B
    const size_t OFF_CUR   = OFF_START + 8192;         //      8,192 B
    const size_t OFF_PERM  = OFF_CUR + 8192;           //     65,536 B
    const size_t OFF_W     = OFF_PERM + 65536;         //     65,536 B
    const size_t OFF_KI8   = OFF_W + 65536;            //  1,048,576 B

    char*   qi8    = ws + OFF_QI8;
    u64*    rowpack= (u64*)(ws + OFF_ROW);
    u32*    cnt    = (u32*)(ws + OFF_CNT);
    int*    cmax   = (int*)(ws + OFF_CMAX);
    u32*    start  = (u32*)(ws + OFF_START);
    u32*    cursor = (u32*)(ws + OFF_CUR);
    u32*    perm   = (u32*)(ws + OFF_PERM);
    float*  wval   = (float*)(ws + OFF_W);
    char*   ki8    = ws + OFF_KI8;

    // rowpack packed values are always >0 -> 0-init acts as -inf; cnt zeroed too
    hipMemsetAsync(ws + OFF_ROW, 0, 131072 + 8192, stream);
    // colmax init to large negative int (0x80808080 = -2.1e9 < any score)
    hipMemsetAsync(ws + OFF_CMAX, 0x80, 8192, stream);

    k_prep<<<N_Q + M_SLOTS, 128, 0, stream>>>(query, keys, qi8, ki8);

    dim3 g2(M_SLOTS / 128, N_Q / 128);  // 16 x 128
    k_score<<<g2, 256, 0, stream>>>(qi8, ki8, rowpack, cmax);

    k_hist<<<N_Q / 256, 256, 0, stream>>>(rowpack, cnt);
    k_scan<<<1, 256, 0, stream>>>(cnt, start, cursor);
    k_fill<<<N_Q / 256, 256, 0, stream>>>(rowpack, cmax, cursor, perm, wval);
    k_gather_final<<<M_SLOTS, 128, 0, stream>>>(qi8, start, cnt, perm, wval, keys, out);
}